// Round 2
// baseline (685.381 us; speedup 1.0000x reference)
//
#include <hip/hip_runtime.h>
#include <math.h>

// Problem constants: B=512, NQ=1, G=1000, H=8, IN=256, E=128, KD=16
#define GG    1000
#define HH    8
#define KDIM  16
#define EDIM  128
#define INDIM 256

// ---------------- K1: per-b  emb = din@Wemb^T + b ; Q = emb@Wq * 1/sqrt(KD) ----
__global__ __launch_bounds__(128) void k1_embq(
    const float* __restrict__ dIn,   // (B,256)
    const float* __restrict__ Wemb,  // (128,256)
    const float* __restrict__ bemb,  // (128)
    const float* __restrict__ Wq,    // (8,128,16)
    float* __restrict__ qout,        // ws: (B,128) = (B,H,KD)
    int B)
{
    const int b = blockIdx.x, t = threadIdx.x;
    __shared__ __align__(16) float s_din[INDIM];
    __shared__ float s_emb[EDIM];

    s_din[t]       = dIn[(size_t)b * INDIM + t];
    s_din[t + 128] = dIn[(size_t)b * INDIM + t + 128];
    __syncthreads();

    float acc = bemb[t];
    const float* w = Wemb + (size_t)t * INDIM;
    #pragma unroll 4
    for (int i = 0; i < INDIM; i += 4) {
        float4 wv = *(const float4*)(w + i);
        acc += wv.x * s_din[i] + wv.y * s_din[i + 1] +
               wv.z * s_din[i + 2] + wv.w * s_din[i + 3];
    }
    s_emb[t] = acc;
    __syncthreads();

    const int h = t >> 4, k = t & 15;
    float q = 0.f;
    const float* wq = Wq + (size_t)h * EDIM * KDIM + k;
    #pragma unroll 8
    for (int e = 0; e < EDIM; ++e) q += s_emb[e] * wq[e * KDIM];
    qout[(size_t)b * EDIM + t] = q * 0.25f;   // fold 1/sqrt(16)
}

// ---------------- K2: per-(h,b) attention -> heads[b, h*16+k] ----------------
// Restructured for memory-level parallelism: all loads of a phase are issued
// into registers BEFORE any consumption (no per-iteration waitcnt serialization).
__global__ __launch_bounds__(256) void k2_attn(
    const float* __restrict__ K,     // (8,B,1000,16)
    const float* __restrict__ V,     // (8,B,1000,16)
    const int*   __restrict__ mask,  // (B,1000)
    const float* __restrict__ qin,   // ws: (B,128)
    float* __restrict__ headsout,    // ws: (B,128)
    int B)
{
    const int bx = blockIdx.x;
    const int b = bx % B, h = bx / B;
    const int t = threadIdx.x;

    __shared__ float s_attn[GG];
    __shared__ float s_red[8];
    __shared__ __align__(16) float s_wp[4][16];
    __shared__ float s_bmax, s_binv;

    // q broadcast: one 64B line, all lanes same address (L1 broadcast)
    const float4* qp = (const float4*)(qin + (size_t)b * EDIM + h * KDIM);
    float4 q0 = qp[0], q1 = qp[1], q2 = qp[2], q3 = qp[3];

    const float* Kh = K + ((size_t)h * B + b) * (size_t)(GG * KDIM);
    const int*   mb = mask + (size_t)b * GG;

    // --- phase 1: mask (4 coalesced loads, no LDS roundtrip) then 16 K loads in flight
    int mk[4];
    #pragma unroll
    for (int i = 0; i < 4; ++i) {
        int g = t + 256 * i;
        mk[i] = (g < GG) ? mb[g] : 0;
    }
    float4 kr[4][4];
    #pragma unroll
    for (int i = 0; i < 4; ++i) {
        int g = t + 256 * i;
        if (mk[i] != 0) {
            const float4* kp = (const float4*)(Kh + (size_t)g * KDIM);
            kr[i][0] = kp[0]; kr[i][1] = kp[1]; kr[i][2] = kp[2]; kr[i][3] = kp[3];
        }
    }
    float c[4];
    float lmax = -1e30f;
    #pragma unroll
    for (int i = 0; i < 4; ++i) {
        float cc = -1e30f;
        if (mk[i] != 0) {
            cc  = q0.x * kr[i][0].x + q0.y * kr[i][0].y + q0.z * kr[i][0].z + q0.w * kr[i][0].w;
            cc += q1.x * kr[i][1].x + q1.y * kr[i][1].y + q1.z * kr[i][1].z + q1.w * kr[i][1].w;
            cc += q2.x * kr[i][2].x + q2.y * kr[i][2].y + q2.z * kr[i][2].z + q2.w * kr[i][2].w;
            cc += q3.x * kr[i][3].x + q3.y * kr[i][3].y + q3.z * kr[i][3].z + q3.w * kr[i][3].w;
        }
        c[i] = cc;
        lmax = fmaxf(lmax, cc);
    }

    // --- block max (wave shuffle, then 4 waves via LDS)
    #pragma unroll
    for (int off = 32; off; off >>= 1) lmax = fmaxf(lmax, __shfl_xor(lmax, off));
    const int wid = t >> 6;
    if ((t & 63) == 0) s_red[wid] = lmax;
    __syncthreads();
    if (t == 0) s_bmax = fmaxf(fmaxf(s_red[0], s_red[1]), fmaxf(s_red[2], s_red[3]));
    __syncthreads();
    const float m = s_bmax;

    // --- exp from registers (no s_attn re-read) + block sum
    float lsum = 0.f;
    #pragma unroll
    for (int i = 0; i < 4; ++i) {
        int g = t + 256 * i;
        if (g < GG) {
            float e = __expf(c[i] - m);   // masked rows underflow to exactly 0
            s_attn[g] = e;
            lsum += e;
        }
    }
    #pragma unroll
    for (int off = 32; off; off >>= 1) lsum += __shfl_xor(lsum, off);
    if ((t & 63) == 0) s_red[4 + wid] = lsum;
    __syncthreads();
    if (t == 0) s_binv = 1.f / (s_red[4] + s_red[5] + s_red[6] + s_red[7]);
    __syncthreads();   // also orders s_attn writes before phase-4 reads

    // --- attn . V : 64 g-subgroups x 4 float4-slots, 8-deep load batching
    const int sub = t >> 2, k4 = t & 3;
    const float* Vh = V + ((size_t)h * B + b) * (size_t)(GG * KDIM);
    float4 acc = make_float4(0.f, 0.f, 0.f, 0.f);
    #pragma unroll
    for (int half = 0; half < 16; half += 8) {
        float a8[8]; float4 v8[8];
        #pragma unroll
        for (int j = 0; j < 8; ++j) {
            int g = sub + (half + j) * 64;
            a8[j] = (g < GG) ? s_attn[g] : 0.f;
        }
        #pragma unroll
        for (int j = 0; j < 8; ++j) {
            int g = sub + (half + j) * 64;
            if (a8[j] != 0.f) v8[j] = *(const float4*)(Vh + (size_t)g * KDIM + k4 * 4);
        }
        #pragma unroll
        for (int j = 0; j < 8; ++j) {
            if (a8[j] != 0.f) {
                acc.x += a8[j] * v8[j].x; acc.y += a8[j] * v8[j].y;
                acc.z += a8[j] * v8[j].z; acc.w += a8[j] * v8[j].w;
            }
        }
    }

    // --- reduce over the 16 subs within each wave via shfl-xor (lane bits 2..5)
    #pragma unroll
    for (int off = 4; off <= 32; off <<= 1) {
        acc.x += __shfl_xor(acc.x, off);
        acc.y += __shfl_xor(acc.y, off);
        acc.z += __shfl_xor(acc.z, off);
        acc.w += __shfl_xor(acc.w, off);
    }
    const int wl = t & 63;
    if (wl < 4) *(float4*)&s_wp[wid][wl * 4] = acc;   // wl == k4 for wl<4
    __syncthreads();
    if (t < 16) {
        float s = s_wp[0][t] + s_wp[1][t] + s_wp[2][t] + s_wp[3][t];
        headsout[(size_t)b * EDIM + h * KDIM + t] = s * s_binv;
    }
}

// ------------- K2b: per-b ctx = heads@Wout ; q2 = ctx@WQ2 * 1/sqrt(128) ------
// Hoisted out of K3 (was redundantly computed 4x per b and serialized K3's
// prologue before any Vout load could issue).
__global__ __launch_bounds__(128) void k2b_q2(
    const float* __restrict__ headsin, // ws: (B,128)
    const float* __restrict__ Wout,    // (8,16,128) = (128,128)
    const float* __restrict__ WQ2,     // (128,128)
    float* __restrict__ q2out,         // ws: (B,128)
    int B)
{
    const int b = blockIdx.x, t = threadIdx.x;
    __shared__ float s_heads[EDIM];
    __shared__ float s_ctx[EDIM];

    s_heads[t] = headsin[(size_t)b * EDIM + t];
    __syncthreads();
    float acc = 0.f;
    #pragma unroll 8
    for (int j = 0; j < EDIM; ++j) acc += s_heads[j] * Wout[(size_t)j * EDIM + t];
    s_ctx[t] = acc;
    __syncthreads();
    float a2 = 0.f;
    #pragma unroll 8
    for (int e = 0; e < EDIM; ++e) a2 += s_ctx[e] * WQ2[(size_t)e * EDIM + t];
    q2out[(size_t)b * EDIM + t] = a2 * 0.08838834764831845f;  // fold 1/sqrt(128)
}

// ------------- K3: per-(b, quarter) z = q2 . Vout rows, 8-deep load batching -
__global__ __launch_bounds__(256) void k3_out(
    const float* __restrict__ Vout,    // (B,1000,128)
    const float* __restrict__ q2in,    // ws: (B,128)
    float* __restrict__ out,           // (B,1000)
    int B)
{
    const int bx = blockIdx.x;
    const int b = bx >> 2, chunk = bx & 3;
    const int t = threadIdx.x;
    const int lane = t & 31;
    const int rowoff = t >> 5;  // 0..7

    const float4 q = ((const float4*)(q2in + (size_t)b * EDIM))[lane];
    const float* Vo = Vout + (size_t)b * (size_t)(GG * EDIM);
    const int g0 = chunk * (GG / 4);
    const int g1 = g0 + (GG / 4);   // 250 rows per chunk

    // rows r = g0 + rowoff + it*64 + j*8 cover g0..g0+255 (guarded to <g1)
    for (int it = 0; it < 4; ++it) {
        const int rbase = g0 + rowoff + it * 64;
        float4 v4[8];
        bool ok[8];
        #pragma unroll
        for (int j = 0; j < 8; ++j) {
            int g = rbase + j * 8;
            ok[j] = (g < g1);
            if (ok[j]) v4[j] = ((const float4*)(Vo + (size_t)g * EDIM))[lane];
        }
        #pragma unroll
        for (int j = 0; j < 8; ++j) {
            if (ok[j]) {
                float acc = v4[j].x * q.x + v4[j].y * q.y + v4[j].z * q.z + v4[j].w * q.w;
                #pragma unroll
                for (int off = 16; off; off >>= 1) acc += __shfl_xor(acc, off, 32);
                if (lane == 0) out[(size_t)b * GG + (rbase + j * 8)] = 10.f * tanhf(acc);
            }
        }
    }
}

extern "C" void kernel_launch(void* const* d_in, const int* in_sizes, int n_in,
                              void* d_out, int out_size, void* d_ws, size_t ws_size,
                              hipStream_t stream) {
    const float* dIn  = (const float*)d_in[0];
    const float* K    = (const float*)d_in[1];
    const float* V    = (const float*)d_in[2];
    const float* Vout = (const float*)d_in[3];
    const int*   mask = (const int*)d_in[4];
    const float* Wemb = (const float*)d_in[5];
    const float* bemb = (const float*)d_in[6];
    const float* Wq   = (const float*)d_in[7];
    const float* Wout = (const float*)d_in[8];
    const float* WQ2  = (const float*)d_in[9];
    float* out = (float*)d_out;

    const int B = in_sizes[0] / INDIM;
    float* ws_q     = (float*)d_ws;                 // B*128 floats
    float* ws_heads = ws_q + (size_t)B * EDIM;      // B*128 floats
    float* ws_q2    = ws_heads + (size_t)B * EDIM;  // B*128 floats

    k1_embq<<<dim3(B), dim3(128), 0, stream>>>(dIn, Wemb, bemb, Wq, ws_q, B);
    k2_attn<<<dim3(HH * B), dim3(256), 0, stream>>>(K, V, mask, ws_q, ws_heads, B);
    k2b_q2<<<dim3(B), dim3(128), 0, stream>>>(ws_heads, Wout, WQ2, ws_q2, B);
    k3_out<<<dim3(B * 4), dim3(256), 0, stream>>>(Vout, ws_q2, out, B);
}